// Round 6
// baseline (318.191 us; speedup 1.0000x reference)
//
#include <hip/hip_runtime.h>
#include <hip/hip_bf16.h>
#include <stdint.h>
#include <math.h>

// ---------------------------------------------------------------------------
// LinkPredictor: out = minmax_norm(E @ E^T)[block-diag strict upper triangle]
// N=16384 (128 graphs x 128), D=512.
// R6: two-pass min/max. Pass 1: i8 MFMA (2x bf16 rate) over all 8256 upper-tri
// tiles -> per-tile int min/max (localization only; dot err sigma~0.47 units,
// margin 8 units = 17 sigma). Pass 2: bf16 recompute of flagged extreme tiles
// (~5-10) + the 128 diagonal tiles (bf16 needed for output values anyway;
// they contain the global max ||e||^2). Output path stays bf16-exact.
// A/B layout robustness: both operands loaded with the same slot convention,
// so any internal k-permutation cancels in the dot product; row permutations
// don't affect per-tile min/max.
// ---------------------------------------------------------------------------

typedef __attribute__((ext_vector_type(8))) __bf16 bf16x8;
typedef __attribute__((ext_vector_type(16))) float floatx16;
typedef __attribute__((ext_vector_type(4))) int intx4;
typedef __attribute__((ext_vector_type(16))) int intx16;

#define AS1 __attribute__((address_space(1)))
#define AS3 __attribute__((address_space(3)))

static constexpr int DIM     = 512;
static constexpr int NTILE   = 128;
static constexpr int NPART   = NTILE * (NTILE + 1) / 2;  // 8256 upper-tri tiles
static constexpr int CAP     = 512;                      // refine-list capacity
static constexpr float QS    = 19.5f;                    // i8 quant scale
static constexpr int MARGIN_I = 3042;                    // 8.0 sims-units * QS^2

// ctrl (ints): [0] fkey_min [1] fkey_max [2] i8 gmin [3] i8 gmax [4] count

static __device__ __forceinline__ unsigned short f2bf_rne(float f) {
  unsigned int u = __float_as_uint(f);
  u += 0x7fffu + ((u >> 16) & 1u);
  return (unsigned short)(u >> 16);
}
// monotone float<->int keys for atomicMin/Max on floats
static __device__ __forceinline__ int fkey(float f) {
  int s = __float_as_int(f);
  return s >= 0 ? s : (s ^ 0x7fffffff);
}
static __device__ __forceinline__ float funkey(int k) {
  return __int_as_float(k >= 0 ? k : (k ^ 0x7fffffff));
}
// bf16 tile swizzle (R2-proven): permute the 8 16B-chunks per row
static __device__ __forceinline__ int swz8(int row, int c8) {
  return c8 ^ (row & 7);
}
// i8 tile swizzle: permute the 4 16B-chunks per row; rows 16 apart collide
// -> 2-way max (free per m136)
static __device__ __forceinline__ int swz4(int row, int c4) {
  return c4 ^ (row & 3) ^ ((row >> 2) & 3);
}
// linear upper-triangle index -> (tr, tc), tc >= tr
static __device__ __forceinline__ void tri_decode(int bi, int& tr_, int& tc_) {
  int t = (int)((257.0 - sqrt(66049.0 - 8.0 * (double)bi)) * 0.5);
  if (t < 0) t = 0;
  if (t > 127) t = 127;
  while (t * (257 - t) / 2 > bi) --t;
  while (t < 127 && (t + 1) * (256 - t) / 2 <= bi) ++t;
  tr_ = t;
  tc_ = t + (bi - t * (257 - t) / 2);
}

// ---- kernel 1: fp32 -> bf16 + i8, init ctrl --------------------------------
__global__ void k_convert(const float* __restrict__ in,
                          unsigned short* __restrict__ bf,
                          char* __restrict__ q,
                          int* __restrict__ ctrl, int n4) {
  int i = blockIdx.x * blockDim.x + threadIdx.x;
  if (i == 0) {
    ctrl[0] = 0x7fffffff; ctrl[1] = (int)0x80000000;   // fkey min/max
    ctrl[2] = 0x7fffffff; ctrl[3] = (int)0x80000000;   // i8 gmin/gmax
    ctrl[4] = 0;                                       // refine count
  }
  if (i >= n4) return;
  float4 v = ((const float4*)in)[i];
  ushort4 o;
  o.x = f2bf_rne(v.x); o.y = f2bf_rne(v.y);
  o.z = f2bf_rne(v.z); o.w = f2bf_rne(v.w);
  ((ushort4*)bf)[i] = o;
  int qx = __float2int_rn(v.x * QS), qy = __float2int_rn(v.y * QS);
  int qz = __float2int_rn(v.z * QS), qw = __float2int_rn(v.w * QS);
  char4 c;
  c.x = (char)min(127, max(-127, qx));
  c.y = (char)min(127, max(-127, qy));
  c.z = (char)min(127, max(-127, qz));
  c.w = (char)min(127, max(-127, qw));
  ((char4*)q)[i] = c;
}

// ---- kernel 2: i8 min/max GEMM over all 8256 upper-tri tiles ---------------
// 256 thr = 4 waves (2x2), each wave 64x64 via 2x2 of 32x32x32 i8 MFMA, BK=64.
__global__ __launch_bounds__(256) void k_i8_minmax(
    const char* __restrict__ Eq,
    int2* __restrict__ ipartials,
    int* __restrict__ ctrl) {
  int tr, tc;
  tri_decode(blockIdx.x, tr, tc);

  const int tid = threadIdx.x;
  __shared__ __align__(16) char lA8[128 * 64];
  __shared__ __align__(16) char lB8[128 * 64];
  __shared__ int2 redbuf[4];

  const int w = tid >> 6, lane = tid & 63;
  const int wr = w >> 1, wc = w & 1;
  const int l31 = lane & 31;
  const int kg  = lane >> 5;

  intx16 acc[2][2];
#pragma unroll
  for (int i = 0; i < 2; i++)
#pragma unroll
    for (int j = 0; j < 2; j++)
#pragma unroll
      for (int r = 0; r < 16; r++) acc[i][j][r] = 0;

  const int rowBaseA = tr * 128;
  const int rowBaseB = tc * 128;

  for (int kb = 0; kb < 8; kb++) {             // K = 512 = 8 * BK(64)
    const int kBase = kb * 64;
    // stage 128 rows x 4 chunks(16B) per tile; slot (row,c4) holds global
    // chunk swz4(row,c4)
#pragma unroll
    for (int j = 0; j < 2; j++) {
      int cb  = (w * 2 + j) * 64;              // wave-uniform chunk base
      int p   = cb + lane;
      int row = p >> 2, c4 = p & 3;
      int sc4 = swz4(row, c4);
      const char* gA = Eq + (size_t)(rowBaseA + row) * DIM + kBase + sc4 * 16;
      const char* gB = Eq + (size_t)(rowBaseB + row) * DIM + kBase + sc4 * 16;
      __builtin_amdgcn_global_load_lds((const AS1 unsigned int*)gA,
                                       (AS3 unsigned int*)(lA8 + p * 16), 16, 0, 0);
      __builtin_amdgcn_global_load_lds((const AS1 unsigned int*)gB,
                                       (AS3 unsigned int*)(lB8 + p * 16), 16, 0, 0);
    }
    __syncthreads();

#pragma unroll
    for (int ks = 0; ks < 2; ks++) {           // 2 k-steps of 32
      intx4 af[2], bfv[2];
      const int c4 = ks * 2 + kg;
#pragma unroll
      for (int t = 0; t < 2; t++) {
        int ra = wr * 64 + t * 32 + l31;
        int rb = wc * 64 + t * 32 + l31;
        af[t]  = *(const intx4*)(lA8 + ra * 64 + swz4(ra, c4) * 16);
        bfv[t] = *(const intx4*)(lB8 + rb * 64 + swz4(rb, c4) * 16);
      }
#pragma unroll
      for (int ti = 0; ti < 2; ti++)
#pragma unroll
        for (int tj = 0; tj < 2; tj++)
          acc[ti][tj] = __builtin_amdgcn_mfma_i32_32x32x32_i8(
              af[ti], bfv[tj], acc[ti][tj], 0, 0, 0);
    }
    __syncthreads();
  }

  int vmin = 0x7fffffff, vmax = (int)0x80000000;
#pragma unroll
  for (int ti = 0; ti < 2; ti++)
#pragma unroll
    for (int tj = 0; tj < 2; tj++)
#pragma unroll
      for (int r = 0; r < 16; r++) {
        int v = acc[ti][tj][r];
        vmin = min(vmin, v);
        vmax = max(vmax, v);
      }
#pragma unroll
  for (int m_ = 32; m_ >= 1; m_ >>= 1) {
    vmin = min(vmin, __shfl_xor(vmin, m_));
    vmax = max(vmax, __shfl_xor(vmax, m_));
  }
  if (lane == 0) redbuf[w] = make_int2(vmin, vmax);
  __syncthreads();
  if (tid == 0) {
    int mn = redbuf[0].x, mx = redbuf[0].y;
    for (int i = 1; i < 4; i++) {
      mn = min(mn, redbuf[i].x);
      mx = max(mx, redbuf[i].y);
    }
    ipartials[blockIdx.x] = make_int2(mn, mx);
    atomicMin(&ctrl[2], mn);
    atomicMax(&ctrl[3], mx);
  }
}

// ---- kernel 3: bf16 diagonal tiles (exact values + min/max) ----------------
// A==B tile: stage once, read both fragment sets from it. (R2-proven body)
__global__ __launch_bounds__(256) void k_diag(
    const unsigned short* __restrict__ E,
    float* __restrict__ diagblocks,
    int* __restrict__ ctrl) {
  const int tg  = blockIdx.x;                  // graph / diag tile index
  const int tid = threadIdx.x;
  __shared__ __align__(16) unsigned short lA[128 * 64];
  __shared__ float2 redbuf[4];

  const int w = tid >> 6, lane = tid & 63;
  const int wr = w >> 1, wc = w & 1;
  const int l31 = lane & 31;
  const int kg  = lane >> 5;

  floatx16 acc[2][2];
#pragma unroll
  for (int i = 0; i < 2; i++)
#pragma unroll
    for (int j = 0; j < 2; j++)
#pragma unroll
      for (int r = 0; r < 16; r++) acc[i][j][r] = 0.f;

  const int rowBase = tg * 128;

  for (int kb = 0; kb < 8; kb++) {
    const int kBase = kb * 64;
#pragma unroll
    for (int j = 0; j < 4; j++) {
      int cb  = (w * 4 + j) * 64;
      int p   = cb + lane;
      int row = p >> 3, c8 = p & 7;
      int sc8 = swz8(row, c8);
      const unsigned short* gA = E + (size_t)(rowBase + row) * DIM + kBase + sc8 * 8;
      __builtin_amdgcn_global_load_lds((const AS1 unsigned int*)gA,
                                       (AS3 unsigned int*)(lA + cb * 8), 16, 0, 0);
    }
    __syncthreads();

#pragma unroll
    for (int ks = 0; ks < 4; ks++) {
      bf16x8 af[2], bfv[2];
      const int c8 = ks * 2 + kg;
#pragma unroll
      for (int t = 0; t < 2; t++) {
        int ra = wr * 64 + t * 32 + l31;
        int rb = wc * 64 + t * 32 + l31;
        af[t]  = *(const bf16x8*)(lA + (ra * 8 + swz8(ra, c8)) * 8);
        bfv[t] = *(const bf16x8*)(lA + (rb * 8 + swz8(rb, c8)) * 8);
      }
#pragma unroll
      for (int ti = 0; ti < 2; ti++)
#pragma unroll
        for (int tj = 0; tj < 2; tj++)
          acc[ti][tj] = __builtin_amdgcn_mfma_f32_32x32x16_bf16(
              af[ti], bfv[tj], acc[ti][tj], 0, 0, 0);
    }
    __syncthreads();
  }

  // min/max -> fkey atomics
  float vmin = 3.4e38f, vmax = -3.4e38f;
#pragma unroll
  for (int ti = 0; ti < 2; ti++)
#pragma unroll
    for (int tj = 0; tj < 2; tj++)
#pragma unroll
      for (int r = 0; r < 16; r++) {
        float v = acc[ti][tj][r];
        vmin = fminf(vmin, v);
        vmax = fmaxf(vmax, v);
      }
#pragma unroll
  for (int m_ = 32; m_ >= 1; m_ >>= 1) {
    vmin = fminf(vmin, __shfl_xor(vmin, m_));
    vmax = fmaxf(vmax, __shfl_xor(vmax, m_));
  }
  if (lane == 0) redbuf[w] = make_float2(vmin, vmax);
  __syncthreads();
  if (tid == 0) {
    float mn = redbuf[0].x, mx = redbuf[0].y;
    for (int i = 1; i < 4; i++) {
      mn = fminf(mn, redbuf[i].x);
      mx = fmaxf(mx, redbuf[i].y);
    }
    atomicMin(&ctrl[0], fkey(mn));
    atomicMax(&ctrl[1], fkey(mx));
  }

  // store raw block (symmetric -> transpose-immune)
  float* Bout = diagblocks + (size_t)tg * (128 * 128);
#pragma unroll
  for (int ti = 0; ti < 2; ti++) {
#pragma unroll
    for (int tj = 0; tj < 2; tj++) {
      int cbase = wc * 64 + tj * 32 + l31;     // C/D: col = lane & 31
#pragma unroll
      for (int r = 0; r < 16; r++) {
        int row = wr * 64 + ti * 32 + (r & 3) + 8 * (r >> 2) + 4 * kg;
        Bout[row * 128 + cbase] = acc[ti][tj][r];
      }
    }
  }
}

// ---- kernel 4: flag candidate extreme tiles --------------------------------
__global__ void k_flag(const int2* __restrict__ ipartials,
                       int* __restrict__ ctrl, int* __restrict__ list) {
  int i = blockIdx.x * blockDim.x + threadIdx.x;
  if (i >= NPART) return;
  int gmin = ctrl[2], gmax = ctrl[3];
  int2 p = ipartials[i];
  if (p.x <= gmin + MARGIN_I || p.y >= gmax - MARGIN_I) {
    int pos = atomicAdd(&ctrl[4], 1);
    if (pos < CAP) {
      int tr, tc;
      tri_decode(i, tr, tc);
      list[pos] = (tr << 8) | tc;
    }
  }
}

// ---- kernel 5: bf16 recompute of flagged tiles -> exact min/max ------------
__global__ __launch_bounds__(256) void k_refine(
    const unsigned short* __restrict__ E,
    const int* __restrict__ list, int* __restrict__ ctrl) {
  int cnt = ctrl[4];
  if (cnt > CAP) cnt = CAP;
  if ((int)blockIdx.x >= cnt) return;
  const int enc = list[blockIdx.x];
  const int tr = enc >> 8, tc = enc & 255;

  const int tid = threadIdx.x;
  __shared__ __align__(16) unsigned short lA[128 * 64];
  __shared__ __align__(16) unsigned short lB[128 * 64];
  __shared__ float2 redbuf[4];

  const int w = tid >> 6, lane = tid & 63;
  const int wr = w >> 1, wc = w & 1;
  const int l31 = lane & 31;
  const int kg  = lane >> 5;

  floatx16 acc[2][2];
#pragma unroll
  for (int i = 0; i < 2; i++)
#pragma unroll
    for (int j = 0; j < 2; j++)
#pragma unroll
      for (int r = 0; r < 16; r++) acc[i][j][r] = 0.f;

  const int rowBaseA = tr * 128;
  const int rowBaseB = tc * 128;

  for (int kb = 0; kb < 8; kb++) {
    const int kBase = kb * 64;
#pragma unroll
    for (int j = 0; j < 4; j++) {
      int cb  = (w * 4 + j) * 64;
      int p   = cb + lane;
      int row = p >> 3, c8 = p & 7;
      int sc8 = swz8(row, c8);
      const unsigned short* gA = E + (size_t)(rowBaseA + row) * DIM + kBase + sc8 * 8;
      const unsigned short* gB = E + (size_t)(rowBaseB + row) * DIM + kBase + sc8 * 8;
      __builtin_amdgcn_global_load_lds((const AS1 unsigned int*)gA,
                                       (AS3 unsigned int*)(lA + cb * 8), 16, 0, 0);
      __builtin_amdgcn_global_load_lds((const AS1 unsigned int*)gB,
                                       (AS3 unsigned int*)(lB + cb * 8), 16, 0, 0);
    }
    __syncthreads();

#pragma unroll
    for (int ks = 0; ks < 4; ks++) {
      bf16x8 af[2], bfv[2];
      const int c8 = ks * 2 + kg;
#pragma unroll
      for (int t = 0; t < 2; t++) {
        int ra = wr * 64 + t * 32 + l31;
        int rb = wc * 64 + t * 32 + l31;
        af[t]  = *(const bf16x8*)(lA + (ra * 8 + swz8(ra, c8)) * 8);
        bfv[t] = *(const bf16x8*)(lB + (rb * 8 + swz8(rb, c8)) * 8);
      }
#pragma unroll
      for (int ti = 0; ti < 2; ti++)
#pragma unroll
        for (int tj = 0; tj < 2; tj++)
          acc[ti][tj] = __builtin_amdgcn_mfma_f32_32x32x16_bf16(
              af[ti], bfv[tj], acc[ti][tj], 0, 0, 0);
    }
    __syncthreads();
  }

  float vmin = 3.4e38f, vmax = -3.4e38f;
#pragma unroll
  for (int ti = 0; ti < 2; ti++)
#pragma unroll
    for (int tj = 0; tj < 2; tj++)
#pragma unroll
      for (int r = 0; r < 16; r++) {
        float v = acc[ti][tj][r];
        vmin = fminf(vmin, v);
        vmax = fmaxf(vmax, v);
      }
#pragma unroll
  for (int m_ = 32; m_ >= 1; m_ >>= 1) {
    vmin = fminf(vmin, __shfl_xor(vmin, m_));
    vmax = fmaxf(vmax, __shfl_xor(vmax, m_));
  }
  if (lane == 0) redbuf[w] = make_float2(vmin, vmax);
  __syncthreads();
  if (tid == 0) {
    float mn = redbuf[0].x, mx = redbuf[0].y;
    for (int i = 1; i < 4; i++) {
      mn = fminf(mn, redbuf[i].x);
      mx = fmaxf(mx, redbuf[i].y);
    }
    atomicMin(&ctrl[0], fkey(mn));
    atomicMax(&ctrl[1], fkey(mx));
  }
}

// ---- kernel 6: gather + normalize ------------------------------------------
__global__ __launch_bounds__(256) void k_gather(
    const int* __restrict__ rix, const int* __restrict__ cix,
    const float* __restrict__ blocks, const int* __restrict__ ctrl,
    float* __restrict__ out, int n) {
  int i = blockIdx.x * blockDim.x + threadIdx.x;
  if (i >= n) return;
  float m   = funkey(ctrl[0]);
  float M   = funkey(ctrl[1]);
  float inv = 1.0f / (M - m + 1e-7f);
  int r = rix[i], c = cix[i];
  int g = r >> 7;
  float v = blocks[((size_t)g << 14) + ((r & 127) << 7) + (c & 127)];
  out[i] = (v - m) * inv;
}

// ---------------------------------------------------------------------------
extern "C" void kernel_launch(void* const* d_in, const int* in_sizes, int n_in,
                              void* d_out, int out_size, void* d_ws, size_t ws_size,
                              hipStream_t stream) {
  const float* emb = (const float*)d_in[0];
  const int* rix   = (const int*)d_in[1];
  const int* cix   = (const int*)d_in[2];

  char* ws = (char*)d_ws;
  int* ctrl           = (int*)ws;                                  // 20 B (pad 256)
  unsigned short* Ebf = (unsigned short*)(ws + 256);               // 16 MB
  // Eq (8 MB) is dead after k_i8_minmax; diagblocks overlays it (stream-ordered)
  char* Eq            = (char*)(ws + 256 + (16u << 20));           // 8 MB
  float* diagblocks   = (float*)(ws + 256 + (16u << 20));          // 8 MB (overlay)
  int2* ipartials     = (int2*)(ws + 256 + (24u << 20));           // 66 KB
  int* list           = (int*)(ws + 256 + (24u << 20) + (128u << 10)); // 2 KB

  int n_elem = in_sizes[0];            // 16384*512
  int n4 = n_elem / 4;
  k_convert<<<(n4 + 255) / 256, 256, 0, stream>>>(emb, Ebf, Eq, ctrl, n4);

  k_i8_minmax<<<NPART, 256, 0, stream>>>(Eq, ipartials, ctrl);

  k_diag<<<NTILE, 256, 0, stream>>>(Ebf, diagblocks, ctrl);

  k_flag<<<(NPART + 255) / 256, 256, 0, stream>>>(ipartials, ctrl, list);

  k_refine<<<CAP, 256, 0, stream>>>(Ebf, list, ctrl);

  k_gather<<<(out_size + 255) / 256, 256, 0, stream>>>(rix, cix, diagblocks,
                                                       ctrl, (float*)d_out,
                                                       out_size);
}

// Round 7
// 208.503 us; speedup vs baseline: 1.5261x; 1.5261x over previous
//
#include <hip/hip_runtime.h>
#include <hip/hip_bf16.h>
#include <stdint.h>
#include <math.h>

// ---------------------------------------------------------------------------
// LinkPredictor: out = minmax_norm(E @ E^T)[block-diag strict upper triangle]
// N=16384 (128 graphs x 128), D=512.
// R7: the K-loop is barrier-latency-bound (~1500cyc/iter regardless of payload,
// R6 evidence), so amortize: i8 BK=128 (16 MFMA + 8 loads per barrier, half the
// barriers, LDS 32KB -> still 4 blocks/CU). Max is provably diagonal
// (Cauchy-Schwarz) -> flag min-side only. Diag tiles fused into the same
// kernel via a bf16 BK=128 path (exact values + exact diag min/max).
// ---------------------------------------------------------------------------

typedef __attribute__((ext_vector_type(8))) __bf16 bf16x8;
typedef __attribute__((ext_vector_type(16))) float floatx16;
typedef __attribute__((ext_vector_type(4))) int intx4;
typedef __attribute__((ext_vector_type(16))) int intx16;

#define AS1 __attribute__((address_space(1)))
#define AS3 __attribute__((address_space(3)))

static constexpr int DIM      = 512;
static constexpr int NTILE    = 128;
static constexpr int NPART    = NTILE * (NTILE + 1) / 2;  // 8256 tiles
static constexpr int CAP      = 512;                      // refine capacity
static constexpr float QS     = 19.5f;                    // i8 quant scale
static constexpr int MARGIN_I = 3042;                     // 8 sims-units * QS^2

// ctrl: [0] fkey_min [1] fkey_max [2] i8 gmin [3] unused [4] refine count

static __device__ __forceinline__ unsigned short f2bf_rne(float f) {
  unsigned int u = __float_as_uint(f);
  u += 0x7fffu + ((u >> 16) & 1u);
  return (unsigned short)(u >> 16);
}
static __device__ __forceinline__ int fkey(float f) {
  int s = __float_as_int(f);
  return s >= 0 ? s : (s ^ 0x7fffffff);
}
static __device__ __forceinline__ float funkey(int k) {
  return __int_as_float(k >= 0 ? k : (k ^ 0x7fffffff));
}
// i8 BK=128: 8 chunks(16B)/row; stagger so rows 8 apart don't collide
static __device__ __forceinline__ int swzi(int row, int c8) {
  return c8 ^ (row & 7) ^ ((row >> 3) & 7);
}
// bf16 BK=128: 16 chunks(16B)/row
static __device__ __forceinline__ int swzd(int row, int c16) {
  return c16 ^ (row & 15);
}
static __device__ __forceinline__ void tri_decode(int bi, int& tr_, int& tc_) {
  int t = (int)((257.0 - sqrt(66049.0 - 8.0 * (double)bi)) * 0.5);
  if (t < 0) t = 0;
  if (t > 127) t = 127;
  while (t * (257 - t) / 2 > bi) --t;
  while (t < 127 && (t + 1) * (256 - t) / 2 <= bi) ++t;
  tr_ = t;
  tc_ = t + (bi - t * (257 - t) / 2);
}

// ---- kernel 1: fp32 -> bf16 + i8, init ctrl --------------------------------
__global__ void k_convert(const float* __restrict__ in,
                          unsigned short* __restrict__ bf,
                          char* __restrict__ q,
                          int* __restrict__ ctrl, int n4) {
  int i = blockIdx.x * blockDim.x + threadIdx.x;
  if (i == 0) {
    ctrl[0] = 0x7fffffff; ctrl[1] = (int)0x80000000;
    ctrl[2] = 0x7fffffff; ctrl[3] = (int)0x80000000;
    ctrl[4] = 0;
  }
  if (i >= n4) return;
  float4 v = ((const float4*)in)[i];
  ushort4 o;
  o.x = f2bf_rne(v.x); o.y = f2bf_rne(v.y);
  o.z = f2bf_rne(v.z); o.w = f2bf_rne(v.w);
  ((ushort4*)bf)[i] = o;
  int qx = __float2int_rn(v.x * QS), qy = __float2int_rn(v.y * QS);
  int qz = __float2int_rn(v.z * QS), qw = __float2int_rn(v.w * QS);
  char4 c;
  c.x = (char)min(127, max(-127, qx));
  c.y = (char)min(127, max(-127, qy));
  c.z = (char)min(127, max(-127, qz));
  c.w = (char)min(127, max(-127, qw));
  ((char4*)q)[i] = c;
}

// ---- kernel 2: fused GEMM ---------------------------------------------------
// off-diag tiles: i8 32x32x32 MFMA, BK=128, per-tile int min -> ipartials.
// diag tiles:     bf16 32x32x16 MFMA, BK=128, exact block values + min/max.
__global__ __launch_bounds__(256) void k_gemm(
    const char* __restrict__ Eq,
    const unsigned short* __restrict__ E,
    int2* __restrict__ ipartials,
    float* __restrict__ diagblocks,
    int* __restrict__ ctrl) {
  int tr, tc;
  tri_decode(blockIdx.x, tr, tc);

  const int tid = threadIdx.x;
  __shared__ __align__(16) char smem[2][128 * 128];   // 32 KB
  __shared__ float2 redbuf[4];
  __shared__ int2 iredbuf[4];

  const int w = tid >> 6, lane = tid & 63;
  const int wr = w >> 1, wc = w & 1;
  const int l31 = lane & 31;
  const int kg  = lane >> 5;

  if (tr != tc) {
    // ---------------- i8 path (min localization) ----------------
    char* lA8 = smem[0];
    char* lB8 = smem[1];
    intx16 acc[2][2];
#pragma unroll
    for (int i = 0; i < 2; i++)
#pragma unroll
      for (int j = 0; j < 2; j++)
#pragma unroll
        for (int r = 0; r < 16; r++) acc[i][j][r] = 0;

    const int rowBaseA = tr * 128;
    const int rowBaseB = tc * 128;

    for (int kb = 0; kb < 4; kb++) {          // K = 512 = 4 * BK(128)
      const int kBase = kb * 128;
      // stage: 128 rows x 8 chunks(16B) per tile; 1024 chunks / 256 thr
#pragma unroll
      for (int j = 0; j < 4; j++) {
        int cb  = (w * 4 + j) * 64;           // wave-uniform chunk base
        int p   = cb + lane;
        int row = p >> 3, c8 = p & 7;
        int sc8 = swzi(row, c8);
        const char* gA = Eq + (size_t)(rowBaseA + row) * DIM + kBase + sc8 * 16;
        const char* gB = Eq + (size_t)(rowBaseB + row) * DIM + kBase + sc8 * 16;
        __builtin_amdgcn_global_load_lds((const AS1 unsigned int*)gA,
                                         (AS3 unsigned int*)(lA8 + p * 16), 16, 0, 0);
        __builtin_amdgcn_global_load_lds((const AS1 unsigned int*)gB,
                                         (AS3 unsigned int*)(lB8 + p * 16), 16, 0, 0);
      }
      __syncthreads();

#pragma unroll
      for (int ks = 0; ks < 4; ks++) {        // 4 k-steps of 32
        intx4 af[2], bfv[2];
        const int c8 = ks * 2 + kg;
#pragma unroll
        for (int t = 0; t < 2; t++) {
          int ra = wr * 64 + t * 32 + l31;
          int rb = wc * 64 + t * 32 + l31;
          af[t]  = *(const intx4*)(lA8 + ra * 128 + swzi(ra, c8) * 16);
          bfv[t] = *(const intx4*)(lB8 + rb * 128 + swzi(rb, c8) * 16);
        }
#pragma unroll
        for (int ti = 0; ti < 2; ti++)
#pragma unroll
          for (int tj = 0; tj < 2; tj++)
            acc[ti][tj] = __builtin_amdgcn_mfma_i32_32x32x32_i8(
                af[ti], bfv[tj], acc[ti][tj], 0, 0, 0);
      }
      __syncthreads();
    }

    int vmin = 0x7fffffff;
#pragma unroll
    for (int ti = 0; ti < 2; ti++)
#pragma unroll
      for (int tj = 0; tj < 2; tj++)
#pragma unroll
        for (int r = 0; r < 16; r++) vmin = min(vmin, acc[ti][tj][r]);
#pragma unroll
    for (int m_ = 32; m_ >= 1; m_ >>= 1)
      vmin = min(vmin, __shfl_xor(vmin, m_));
    if (lane == 0) iredbuf[w] = make_int2(vmin, 0);
    __syncthreads();
    if (tid == 0) {
      int mn = iredbuf[0].x;
      for (int i = 1; i < 4; i++) mn = min(mn, iredbuf[i].x);
      ipartials[blockIdx.x] = make_int2(mn, 0);
      atomicMin(&ctrl[2], mn);
    }
  } else {
    // ---------------- bf16 diagonal path (exact) ----------------
    unsigned short* lA = (unsigned short*)smem[0];  // 128 rows x 128 bf16 = 32KB
    floatx16 acc[2][2];
#pragma unroll
    for (int i = 0; i < 2; i++)
#pragma unroll
      for (int j = 0; j < 2; j++)
#pragma unroll
        for (int r = 0; r < 16; r++) acc[i][j][r] = 0.f;

    const int rowBase = tr * 128;

    for (int kb = 0; kb < 4; kb++) {          // K = 512 = 4 * BK(128)
      const int kBase = kb * 128;
      // stage: 128 rows x 16 chunks(16B) = 2048 chunks / 256 thr
#pragma unroll
      for (int j = 0; j < 8; j++) {
        int cb  = (w * 8 + j) * 64;           // wave-uniform chunk base
        int p   = cb + lane;
        int row = p >> 4, c16 = p & 15;
        int sc = swzd(row, c16);
        const unsigned short* gA =
            E + (size_t)(rowBase + row) * DIM + kBase + sc * 8;
        __builtin_amdgcn_global_load_lds((const AS1 unsigned int*)gA,
                                         (AS3 unsigned int*)(lA + p * 8), 16, 0, 0);
      }
      __syncthreads();

#pragma unroll
      for (int ks = 0; ks < 8; ks++) {        // 8 k-steps of 16
        bf16x8 af[2], bfv[2];
        const int c16 = ks * 2 + kg;
#pragma unroll
        for (int t = 0; t < 2; t++) {
          int ra = wr * 64 + t * 32 + l31;
          int rb = wc * 64 + t * 32 + l31;
          af[t]  = *(const bf16x8*)(lA + ra * 128 + swzd(ra, c16) * 8);
          bfv[t] = *(const bf16x8*)(lA + rb * 128 + swzd(rb, c16) * 8);
        }
#pragma unroll
        for (int ti = 0; ti < 2; ti++)
#pragma unroll
          for (int tj = 0; tj < 2; tj++)
            acc[ti][tj] = __builtin_amdgcn_mfma_f32_32x32x16_bf16(
                af[ti], bfv[tj], acc[ti][tj], 0, 0, 0);
      }
      __syncthreads();
    }

    float vmin = 3.4e38f, vmax = -3.4e38f;
#pragma unroll
    for (int ti = 0; ti < 2; ti++)
#pragma unroll
      for (int tj = 0; tj < 2; tj++)
#pragma unroll
        for (int r = 0; r < 16; r++) {
          float v = acc[ti][tj][r];
          vmin = fminf(vmin, v);
          vmax = fmaxf(vmax, v);
        }
#pragma unroll
    for (int m_ = 32; m_ >= 1; m_ >>= 1) {
      vmin = fminf(vmin, __shfl_xor(vmin, m_));
      vmax = fmaxf(vmax, __shfl_xor(vmax, m_));
    }
    if (lane == 0) redbuf[w] = make_float2(vmin, vmax);
    __syncthreads();
    if (tid == 0) {
      float mn = redbuf[0].x, mx = redbuf[0].y;
      for (int i = 1; i < 4; i++) {
        mn = fminf(mn, redbuf[i].x);
        mx = fmaxf(mx, redbuf[i].y);
      }
      atomicMin(&ctrl[0], fkey(mn));
      atomicMax(&ctrl[1], fkey(mx));   // global max is diagonal (Cauchy-Schwarz)
      ipartials[blockIdx.x] = make_int2(0x7fffffff, 0);  // never flagged
    }

    float* Bout = diagblocks + (size_t)tr * (128 * 128);
#pragma unroll
    for (int ti = 0; ti < 2; ti++) {
#pragma unroll
      for (int tj = 0; tj < 2; tj++) {
        int cbase = wc * 64 + tj * 32 + l31;   // C/D: col = lane & 31
#pragma unroll
        for (int r = 0; r < 16; r++) {
          int row = wr * 64 + ti * 32 + (r & 3) + 8 * (r >> 2) + 4 * kg;
          Bout[row * 128 + cbase] = acc[ti][tj][r];
        }
      }
    }
  }
}

// ---- kernel 3: flag candidate min tiles ------------------------------------
__global__ void k_flag(const int2* __restrict__ ipartials,
                       int* __restrict__ ctrl, int* __restrict__ list) {
  int i = blockIdx.x * blockDim.x + threadIdx.x;
  if (i >= NPART) return;
  int gmin = ctrl[2];
  if (ipartials[i].x <= gmin + MARGIN_I) {
    int pos = atomicAdd(&ctrl[4], 1);
    if (pos < CAP) {
      int tr, tc;
      tri_decode(i, tr, tc);
      list[pos] = (tr << 8) | tc;
    }
  }
}

// ---- kernel 4: bf16 recompute of flagged tiles -> exact min ----------------
__global__ __launch_bounds__(256) void k_refine(
    const unsigned short* __restrict__ E,
    const int* __restrict__ list, int* __restrict__ ctrl) {
  int cnt = ctrl[4];
  if (cnt > CAP) cnt = CAP;
  if ((int)blockIdx.x >= cnt) return;
  const int enc = list[blockIdx.x];
  const int tr = enc >> 8, tc = enc & 255;

  const int tid = threadIdx.x;
  __shared__ __align__(16) unsigned short lA[128 * 64];
  __shared__ __align__(16) unsigned short lB[128 * 64];
  __shared__ float2 redbuf[4];

  const int w = tid >> 6, lane = tid & 63;
  const int wr = w >> 1, wc = w & 1;
  const int l31 = lane & 31;
  const int kg  = lane >> 5;

  floatx16 acc[2][2];
#pragma unroll
  for (int i = 0; i < 2; i++)
#pragma unroll
    for (int j = 0; j < 2; j++)
#pragma unroll
      for (int r = 0; r < 16; r++) acc[i][j][r] = 0.f;

  const int rowBaseA = tr * 128;
  const int rowBaseB = tc * 128;

  for (int kb = 0; kb < 8; kb++) {
    const int kBase = kb * 64;
#pragma unroll
    for (int j = 0; j < 4; j++) {
      int cb  = (w * 4 + j) * 64;
      int p   = cb + lane;
      int row = p >> 3, c8 = p & 7;
      int sc8 = c8 ^ (row & 7);
      const unsigned short* gA = E + (size_t)(rowBaseA + row) * DIM + kBase + sc8 * 8;
      const unsigned short* gB = E + (size_t)(rowBaseB + row) * DIM + kBase + sc8 * 8;
      __builtin_amdgcn_global_load_lds((const AS1 unsigned int*)gA,
                                       (AS3 unsigned int*)(lA + cb * 8), 16, 0, 0);
      __builtin_amdgcn_global_load_lds((const AS1 unsigned int*)gB,
                                       (AS3 unsigned int*)(lB + cb * 8), 16, 0, 0);
    }
    __syncthreads();

#pragma unroll
    for (int ks = 0; ks < 4; ks++) {
      bf16x8 af[2], bfv[2];
      const int c8 = ks * 2 + kg;
#pragma unroll
      for (int t = 0; t < 2; t++) {
        int ra = wr * 64 + t * 32 + l31;
        int rb = wc * 64 + t * 32 + l31;
        af[t]  = *(const bf16x8*)(lA + (ra * 8 + (c8 ^ (ra & 7))) * 8);
        bfv[t] = *(const bf16x8*)(lB + (rb * 8 + (c8 ^ (rb & 7))) * 8);
      }
#pragma unroll
      for (int ti = 0; ti < 2; ti++)
#pragma unroll
        for (int tj = 0; tj < 2; tj++)
          acc[ti][tj] = __builtin_amdgcn_mfma_f32_32x32x16_bf16(
              af[ti], bfv[tj], acc[ti][tj], 0, 0, 0);
    }
    __syncthreads();
  }

  float vmin = 3.4e38f;
#pragma unroll
  for (int ti = 0; ti < 2; ti++)
#pragma unroll
    for (int tj = 0; tj < 2; tj++)
#pragma unroll
      for (int r = 0; r < 16; r++) vmin = fminf(vmin, acc[ti][tj][r]);
#pragma unroll
  for (int m_ = 32; m_ >= 1; m_ >>= 1)
    vmin = fminf(vmin, __shfl_xor(vmin, m_));
  if (lane == 0) redbuf[w] = make_float2(vmin, 0.f);
  __syncthreads();
  if (tid == 0) {
    float mn = redbuf[0].x;
    for (int i = 1; i < 4; i++) mn = fminf(mn, redbuf[i].x);
    atomicMin(&ctrl[0], fkey(mn));
  }
}

// ---- kernel 5: gather + normalize ------------------------------------------
__global__ __launch_bounds__(256) void k_gather(
    const int* __restrict__ rix, const int* __restrict__ cix,
    const float* __restrict__ blocks, const int* __restrict__ ctrl,
    float* __restrict__ out, int n) {
  int i = blockIdx.x * blockDim.x + threadIdx.x;
  if (i >= n) return;
  float m   = funkey(ctrl[0]);
  float M   = funkey(ctrl[1]);
  float inv = 1.0f / (M - m + 1e-7f);
  int r = rix[i], c = cix[i];
  int g = r >> 7;
  float v = blocks[((size_t)g << 14) + ((r & 127) << 7) + (c & 127)];
  out[i] = (v - m) * inv;
}

// ---------------------------------------------------------------------------
extern "C" void kernel_launch(void* const* d_in, const int* in_sizes, int n_in,
                              void* d_out, int out_size, void* d_ws, size_t ws_size,
                              hipStream_t stream) {
  const float* emb = (const float*)d_in[0];
  const int* rix   = (const int*)d_in[1];
  const int* cix   = (const int*)d_in[2];

  char* ws = (char*)d_ws;
  int* ctrl           = (int*)ws;                                  // 20 B (pad 256)
  unsigned short* Ebf = (unsigned short*)(ws + 256);               // 16 MB
  char* Eq            = (char*)(ws + 256 + (16u << 20));           // 8 MB
  float* diagblocks   = (float*)(ws + 256 + (24u << 20));          // 8 MB
  int2* ipartials     = (int2*)(ws + 256 + (32u << 20));           // 66 KB
  int* list           = (int*)(ws + 256 + (32u << 20) + (128u << 10)); // 2 KB

  int n_elem = in_sizes[0];            // 16384*512
  int n4 = n_elem / 4;
  k_convert<<<(n4 + 255) / 256, 256, 0, stream>>>(emb, Ebf, Eq, ctrl, n4);

  k_gemm<<<NPART, 256, 0, stream>>>(Eq, Ebf, ipartials, diagblocks, ctrl);

  k_flag<<<(NPART + 255) / 256, 256, 0, stream>>>(ipartials, ctrl, list);

  k_refine<<<CAP, 256, 0, stream>>>(Ebf, list, ctrl);

  k_gather<<<(out_size + 255) / 256, 256, 0, stream>>>(rix, cix, diagblocks,
                                                       ctrl, (float*)d_out,
                                                       out_size);
}